// Round 1
// baseline (539.259 us; speedup 1.0000x reference)
//
#include <hip/hip_runtime.h>
#include <math.h>

// Phenotype similarity loss: B=8192 anchors, latent D=128, abr D=6.
// out[0]=phenotype_loss, out[1]=mean_abr_similarity, out[2]=num_pos, out[3]=positive_pair_ratio

#define LAT_D 128
#define ABR_D 6
#define SIM_THR 0.8f

// ---------------- kernel 1: L2-normalize latent rows (128 dims) ----------------
// one wave per row, float2 per lane
__global__ __launch_bounds__(256) void k_norm_lat(const float* __restrict__ in,
                                                  float* __restrict__ out, int B) {
    int row = blockIdx.x * 4 + (threadIdx.x >> 6);
    int lane = threadIdx.x & 63;
    if (row >= B) return;
    float2 v = reinterpret_cast<const float2*>(in + (size_t)row * LAT_D)[lane];
    float ss = v.x * v.x + v.y * v.y;
#pragma unroll
    for (int m = 1; m < 64; m <<= 1) ss += __shfl_xor(ss, m);
    float sc = 1.0f / fmaxf(sqrtf(ss), 1e-12f);
    float2 o; o.x = v.x * sc; o.y = v.y * sc;
    reinterpret_cast<float2*>(out + (size_t)row * LAT_D)[lane] = o;
}

// ---------------- kernel 2: L2-normalize abr rows (6 dims) -> stride 8 ----------------
__global__ __launch_bounds__(256) void k_norm_abr(const float* __restrict__ in,
                                                  float* __restrict__ out, int B) {
    int row = blockIdx.x * 256 + threadIdx.x;
    if (row >= B) return;
    float v[ABR_D];
    float ss = 0.f;
#pragma unroll
    for (int d = 0; d < ABR_D; ++d) { v[d] = in[(size_t)row * ABR_D + d]; ss += v[d] * v[d]; }
    float sc = 1.0f / fmaxf(sqrtf(ss), 1e-12f);
#pragma unroll
    for (int d = 0; d < ABR_D; ++d) out[(size_t)row * 8 + d] = v[d] * sc;
    out[(size_t)row * 8 + 6] = 0.f;
    out[(size_t)row * 8 + 7] = 0.f;
}

// ---------------- kernel 3: S_i = sum_{j != i} exp(2*dot(ln_i, ln_j)) ----------------
// Block: 256 threads, owns 32 rows, sweeps half of j-range (512 blocks total).
// LDS tiles padded to stride 132 floats: b-reads land on 8 distinct bank-quads (2-way = free).
__global__ __launch_bounds__(256) void k_rowsums(const float* __restrict__ ln,
                                                 float* __restrict__ Spart, int B) {
    constexpr int LDA = 132;
    __shared__ float As[32 * LDA];
    __shared__ float Bs[64 * LDA];
    int ib = blockIdx.x >> 1;
    int jh = blockIdx.x & 1;
    int i0 = ib * 32;
    int tid = threadIdx.x;

    // stage A tile: 32 rows x 128 = 1024 float4, 4 per thread (coalesced)
#pragma unroll
    for (int it = 0; it < 4; ++it) {
        int idx = it * 256 + tid;
        int row = idx >> 5, c4 = idx & 31;
        float4 v = reinterpret_cast<const float4*>(ln)[(size_t)(i0 + row) * 32 + c4];
        *reinterpret_cast<float4*>(&As[row * LDA + c4 * 4]) = v;
    }

    int ig = tid >> 4;   // 0..15 -> rows {ig, ig+16}
    int jg = tid & 15;   // 0..15 -> cols {jg, jg+16, jg+32, jg+48}
    float se0 = 0.f, se1 = 0.f;
    int gi0 = i0 + ig, gi1 = i0 + ig + 16;
    int jbase = jh * (B / 2);
    int ntiles = (B / 2) / 64;

    for (int jt = 0; jt < ntiles; ++jt) {
        int j0 = jbase + jt * 64;
        __syncthreads();  // protect Bs from previous iteration (and As on iter 0)
        // stage B tile: 64 rows x 128 = 2048 float4, 8 per thread
#pragma unroll
        for (int it = 0; it < 8; ++it) {
            int idx = it * 256 + tid;
            int row = idx >> 5, c4 = idx & 31;
            float4 v = reinterpret_cast<const float4*>(ln)[(size_t)(j0 + row) * 32 + c4];
            *reinterpret_cast<float4*>(&Bs[row * LDA + c4 * 4]) = v;
        }
        __syncthreads();

        float acc[2][4] = {{0.f, 0.f, 0.f, 0.f}, {0.f, 0.f, 0.f, 0.f}};
#pragma unroll
        for (int k = 0; k < LAT_D; k += 4) {
            float4 a0 = *reinterpret_cast<const float4*>(&As[ig * LDA + k]);
            float4 a1 = *reinterpret_cast<const float4*>(&As[(ig + 16) * LDA + k]);
#pragma unroll
            for (int r = 0; r < 4; ++r) {
                float4 b = *reinterpret_cast<const float4*>(&Bs[(jg + 16 * r) * LDA + k]);
                acc[0][r] = fmaf(a0.w, b.w, fmaf(a0.z, b.z, fmaf(a0.y, b.y, fmaf(a0.x, b.x, acc[0][r]))));
                acc[1][r] = fmaf(a1.w, b.w, fmaf(a1.z, b.z, fmaf(a1.y, b.y, fmaf(a1.x, b.x, acc[1][r]))));
            }
        }
#pragma unroll
        for (int r = 0; r < 4; ++r) {
            int gj = j0 + jg + 16 * r;
            float e0 = __expf(2.f * acc[0][r]);
            float e1 = __expf(2.f * acc[1][r]);
            if (gj != gi0) se0 += e0;   // exclude diagonal
            if (gj != gi1) se1 += e1;
        }
    }
    // reduce across the 16 jg-lanes sharing each row (contiguous 16-lane groups)
#pragma unroll
    for (int m = 1; m < 16; m <<= 1) {
        se0 += __shfl_xor(se0, m);
        se1 += __shfl_xor(se1, m);
    }
    if (jg == 0) {
        Spart[(size_t)jh * B + gi0] = se0;
        Spart[(size_t)jh * B + gi1] = se1;
    }
}

// ---------------- kernel 4: pair scan (64x64 tiles) ----------------
// abr sims in fp32 from LDS; positives compacted into LDS list; wave-cooperative
// 128-dim dots for positives; per-block partials to unique global slots.
__global__ __launch_bounds__(256) void k_pairs(const float* __restrict__ ln,
                                               const float* __restrict__ abrn,
                                               const float* __restrict__ Spart,
                                               unsigned int* __restrict__ bcnt,
                                               float* __restrict__ babr,
                                               float* __restrict__ bloss, int B) {
    __shared__ float Ai[64][8];
    __shared__ float Aj[64][8];
    __shared__ float Sv[64];
    __shared__ unsigned int lcount;
    __shared__ unsigned short list[4096];
    __shared__ float wred[4], wabr[4];
    __shared__ unsigned int wcnt[4];

    int i0 = blockIdx.y * 64;
    int j0 = blockIdx.x * 64;
    int tid = threadIdx.x;
    if (tid == 0) lcount = 0;

    if (tid < 128) {
        int row = tid >> 1, h = tid & 1;
        *reinterpret_cast<float4*>(&Ai[row][h * 4]) =
            reinterpret_cast<const float4*>(abrn)[(size_t)(i0 + row) * 2 + h];
    } else {
        int t = tid - 128;
        int row = t >> 1, h = t & 1;
        *reinterpret_cast<float4*>(&Aj[row][h * 4]) =
            reinterpret_cast<const float4*>(abrn)[(size_t)(j0 + row) * 2 + h];
    }
    if (tid < 64) Sv[tid] = Spart[i0 + tid] + Spart[(size_t)B + i0 + tid];
    __syncthreads();

    float pabr = 0.f;
    unsigned int pcnt = 0;
    int ti = tid >> 4, tj = tid & 15;
#pragma unroll
    for (int a = 0; a < 4; ++a) {
        int il = ti * 4 + a;
        int gi = i0 + il;
        float x0 = Ai[il][0], x1 = Ai[il][1], x2 = Ai[il][2];
        float x3 = Ai[il][3], x4 = Ai[il][4], x5 = Ai[il][5];
#pragma unroll
        for (int b = 0; b < 4; ++b) {
            int jl = tj * 4 + b;
            int gj = j0 + jl;
            float sim = x0 * Aj[jl][0] + x1 * Aj[jl][1] + x2 * Aj[jl][2] +
                        x3 * Aj[jl][3] + x4 * Aj[jl][4] + x5 * Aj[jl][5];
            if (sim > SIM_THR && gi != gj) {
                pcnt++;
                pabr += sim;
                unsigned idx = atomicAdd(&lcount, 1u);
                list[idx] = (unsigned short)((il << 6) | jl);
            }
        }
    }
    __syncthreads();

    unsigned n = lcount;
    int wave = tid >> 6, lane = tid & 63;
    float wloss = 0.f;
    for (unsigned e = wave; e < n; e += 4) {
        unsigned p = list[e];
        int il = p >> 6, jl = p & 63;
        float2 va = reinterpret_cast<const float2*>(ln + (size_t)(i0 + il) * LAT_D)[lane];
        float2 vb = reinterpret_cast<const float2*>(ln + (size_t)(j0 + jl) * LAT_D)[lane];
        float d = va.x * vb.x + va.y * vb.y;
#pragma unroll
        for (int m = 1; m < 64; m <<= 1) d += __shfl_xor(d, m);
        float s = 2.f * d;
        wloss += log1pf(Sv[il] * __expf(-s));  // all lanes compute; identical values
    }

    // block-level reduction of partials
#pragma unroll
    for (int m = 1; m < 64; m <<= 1) {
        pabr += __shfl_xor(pabr, m);
        pcnt += __shfl_xor(pcnt, m);
    }
    if (lane == 0) { wred[wave] = wloss; wcnt[wave] = pcnt; wabr[wave] = pabr; }
    __syncthreads();
    if (tid == 0) {
        unsigned c = wcnt[0] + wcnt[1] + wcnt[2] + wcnt[3];
        float ab = wabr[0] + wabr[1] + wabr[2] + wabr[3];
        float lo = wred[0] + wred[1] + wred[2] + wred[3];
        int bid = blockIdx.y * gridDim.x + blockIdx.x;
        bcnt[bid] = c;
        babr[bid] = ab;
        bloss[bid] = lo;
    }
}

// ---------------- kernel 5: final reduce over block partials ----------------
__global__ __launch_bounds__(256) void k_final(const unsigned int* __restrict__ bcnt,
                                               const float* __restrict__ babr,
                                               const float* __restrict__ bloss,
                                               float* __restrict__ out, int nblocks,
                                               float npairs) {
    __shared__ unsigned int sc[4];
    __shared__ float sab[4], slo[4];
    int tid = threadIdx.x;
    unsigned int c = 0;
    float ab = 0.f, lo = 0.f;
    for (int e = tid; e < nblocks; e += 256) {
        c += bcnt[e];
        ab += babr[e];
        lo += bloss[e];
    }
#pragma unroll
    for (int m = 1; m < 64; m <<= 1) {
        c += __shfl_xor(c, m);
        ab += __shfl_xor(ab, m);
        lo += __shfl_xor(lo, m);
    }
    int wave = tid >> 6, lane = tid & 63;
    if (lane == 0) { sc[wave] = c; sab[wave] = ab; slo[wave] = lo; }
    __syncthreads();
    if (tid == 0) {
        unsigned ctot = sc[0] + sc[1] + sc[2] + sc[3];
        float abt = sab[0] + sab[1] + sab[2] + sab[3];
        float lot = slo[0] + slo[1] + slo[2] + slo[3];
        float fn = (float)ctot;
        out[0] = ctot ? lot / fn : 0.f;
        out[1] = ctot ? abt / fn : 0.f;
        out[2] = fn;
        out[3] = fn / npairs;
    }
}

extern "C" void kernel_launch(void* const* d_in, const int* in_sizes, int n_in,
                              void* d_out, int out_size, void* d_ws, size_t ws_size,
                              hipStream_t stream) {
    const float* lat = (const float*)d_in[0];
    const float* abr = (const float*)d_in[1];
    float* out = (float*)d_out;
    int B = in_sizes[1] / ABR_D;  // 8192

    char* ws = (char*)d_ws;
    size_t off = 0;
    float* ln = (float*)(ws + off);          off += (size_t)B * LAT_D * 4;   // 4 MB
    float* abrn = (float*)(ws + off);        off += (size_t)B * 8 * 4;       // 256 KB
    float* Spart = (float*)(ws + off);       off += (size_t)2 * B * 4;       // 64 KB
    int nb = B / 64;                  // 128
    int nblocks = nb * nb;            // 16384
    unsigned int* bcnt = (unsigned int*)(ws + off); off += (size_t)nblocks * 4;
    float* babr = (float*)(ws + off);        off += (size_t)nblocks * 4;
    float* bloss = (float*)(ws + off);       off += (size_t)nblocks * 4;

    k_norm_lat<<<B / 4, 256, 0, stream>>>(lat, ln, B);
    k_norm_abr<<<(B + 255) / 256, 256, 0, stream>>>(abr, abrn, B);
    k_rowsums<<<(B / 32) * 2, 256, 0, stream>>>(ln, Spart, B);
    k_pairs<<<dim3(nb, nb), 256, 0, stream>>>(ln, abrn, Spart, bcnt, babr, bloss, B);
    k_final<<<1, 256, 0, stream>>>(bcnt, babr, bloss, out, nblocks, (float)B * (float)(B - 1));
}

// Round 2
// 271.141 us; speedup vs baseline: 1.9888x; 1.9888x over previous
//
#include <hip/hip_runtime.h>
#include <hip/hip_bf16.h>
#include <math.h>

#define LAT_D 128
#define ABR_D 6
#define SIM_THR 0.8f

typedef __attribute__((ext_vector_type(8))) short short8v;  // 8 bf16 = 4 VGPR
typedef __attribute__((ext_vector_type(4))) float f32x4;

// ---------------- kernel 1: L2-normalize latent rows -> bf16 ----------------
__global__ __launch_bounds__(256) void k_norm_lat(const float* __restrict__ in,
                                                  __hip_bfloat16* __restrict__ out, int B) {
    int row = blockIdx.x * 4 + (threadIdx.x >> 6);
    int lane = threadIdx.x & 63;
    if (row >= B) return;
    float2 v = reinterpret_cast<const float2*>(in + (size_t)row * LAT_D)[lane];
    float ss = v.x * v.x + v.y * v.y;
#pragma unroll
    for (int m = 1; m < 64; m <<= 1) ss += __shfl_xor(ss, m);
    float sc = 1.0f / fmaxf(sqrtf(ss), 1e-12f);
    __hip_bfloat162 o;
    o.x = __float2bfloat16(v.x * sc);
    o.y = __float2bfloat16(v.y * sc);
    reinterpret_cast<__hip_bfloat162*>(out + (size_t)row * LAT_D)[lane] = o;
}

// ---------------- kernel 2: L2-normalize abr rows (6 dims) -> stride 8 ----------------
__global__ __launch_bounds__(256) void k_norm_abr(const float* __restrict__ in,
                                                  float* __restrict__ out, int B) {
    int row = blockIdx.x * 256 + threadIdx.x;
    if (row >= B) return;
    float v[ABR_D];
    float ss = 0.f;
#pragma unroll
    for (int d = 0; d < ABR_D; ++d) { v[d] = in[(size_t)row * ABR_D + d]; ss += v[d] * v[d]; }
    float sc = 1.0f / fmaxf(sqrtf(ss), 1e-12f);
#pragma unroll
    for (int d = 0; d < ABR_D; ++d) out[(size_t)row * 8 + d] = v[d] * sc;
    out[(size_t)row * 8 + 6] = 0.f;
    out[(size_t)row * 8 + 7] = 0.f;
}

// ---------------- fused MFMA GEMM over 128x128 tiles ----------------
// PHASE 0: rowsum partials Sp[bj*2+wc][i] = sum_j exp(2*dot) (diag excluded)
// PHASE 1: positive-mask (fp32 abr sims) + loss = sum log1p(S_i * exp(-s)); block partials.
// LDS (dynamic): As[128][136] bf16 | Bs[128][136] bf16 | (PHASE1) aI[128][8] f32, aJ[128][8] f32
// stride 136 bf16 = 272 B = 68 dwords -> bank 4*row mod 32 -> 2-way conflicts (free).
template <int PHASE>
__global__ __launch_bounds__(256, 2) void k_gemm(const __hip_bfloat16* __restrict__ lnbf,
                                                 const float* __restrict__ abrn,
                                                 const float* __restrict__ Sg,
                                                 float* __restrict__ Sp,
                                                 float* __restrict__ bloss,
                                                 float* __restrict__ babr,
                                                 unsigned* __restrict__ bcnt, int B) {
    extern __shared__ char lds[];
    __hip_bfloat16* As = (__hip_bfloat16*)lds;                 // 34816 B
    __hip_bfloat16* Bs = (__hip_bfloat16*)(lds + 34816);       // 34816 B
    float* aI = (float*)(lds + 69632);                         // 4096 B (PHASE1)
    float* aJ = (float*)(lds + 73728);                         // 4096 B (PHASE1)
    __shared__ unsigned mask_s[512];   // 128 rows x 4 words
    __shared__ float Sv_s[128];
    __shared__ float red_l[4], red_a[4];
    __shared__ unsigned red_c[4];

    int bi = blockIdx.y, bj = blockIdx.x;
    int i0 = bi * 128, j0 = bj * 128;
    int tid = threadIdx.x;

    // ---- stage A/B tiles: 128 rows x 16 chunks(8 bf16) each ----
#pragma unroll
    for (int it = 0; it < 8; ++it) {
        int idx = it * 256 + tid;
        int row = idx >> 4, c = idx & 15;
        float4 va = *reinterpret_cast<const float4*>(lnbf + (size_t)(i0 + row) * LAT_D + c * 8);
        *reinterpret_cast<float4*>(As + row * 136 + c * 8) = va;
        float4 vb = *reinterpret_cast<const float4*>(lnbf + (size_t)(j0 + row) * LAT_D + c * 8);
        *reinterpret_cast<float4*>(Bs + row * 136 + c * 8) = vb;
    }
    if constexpr (PHASE == 1) {
        int row = tid >> 1, h = tid & 1;
        *reinterpret_cast<float4*>(aI + row * 8 + h * 4) =
            *reinterpret_cast<const float4*>(abrn + (size_t)(i0 + row) * 8 + h * 4);
        *reinterpret_cast<float4*>(aJ + row * 8 + h * 4) =
            *reinterpret_cast<const float4*>(abrn + (size_t)(j0 + row) * 8 + h * 4);
        mask_s[tid] = 0;
        mask_s[tid + 256] = 0;
        if (tid < 128) Sv_s[tid] = Sg[i0 + tid];
    }
    __syncthreads();

    // ---- PHASE1: build positive mask from fp32 abr sims ----
    unsigned pcnt = 0;
    float pabr = 0.f;
    if constexpr (PHASE == 1) {
        int ti = tid >> 4, tj = tid & 15;
        float rj[8][6];
#pragma unroll
        for (int b = 0; b < 8; ++b) {
            float4 u0 = *reinterpret_cast<const float4*>(aJ + (tj * 8 + b) * 8);
            float2 u1 = *reinterpret_cast<const float2*>(aJ + (tj * 8 + b) * 8 + 4);
            rj[b][0] = u0.x; rj[b][1] = u0.y; rj[b][2] = u0.z;
            rj[b][3] = u0.w; rj[b][4] = u1.x; rj[b][5] = u1.y;
        }
#pragma unroll
        for (int a = 0; a < 8; ++a) {
            int il = ti * 8 + a;
            int gi = i0 + il;
            float4 v0 = *reinterpret_cast<const float4*>(aI + il * 8);
            float2 v1 = *reinterpret_cast<const float2*>(aI + il * 8 + 4);
            unsigned byte = 0;
#pragma unroll
            for (int b = 0; b < 8; ++b) {
                int gj = j0 + tj * 8 + b;
                float sim = v0.x * rj[b][0] + v0.y * rj[b][1] + v0.z * rj[b][2] +
                            v0.w * rj[b][3] + v1.x * rj[b][4] + v1.y * rj[b][5];
                if (sim > SIM_THR && gi != gj) { byte |= 1u << b; pcnt++; pabr += sim; }
            }
            if (byte) atomicOr(&mask_s[il * 4 + (tj >> 2)], byte << ((tj & 3) * 8));
        }
        __syncthreads();
    }

    // ---- MFMA: each wave computes a 64x64 quadrant ----
    int wave = tid >> 6, l = tid & 63;
    int wr = wave >> 1, wc = wave & 1;
    int lr = l & 15, lg = l >> 4;

    f32x4 acc[4][4];
#pragma unroll
    for (int m = 0; m < 4; ++m)
#pragma unroll
        for (int n = 0; n < 4; ++n) acc[m][n] = (f32x4){0.f, 0.f, 0.f, 0.f};

#pragma unroll
    for (int kk = 0; kk < 4; ++kk) {
        int koff = kk * 32 + lg * 8;
        short8v a[4], b[4];
#pragma unroll
        for (int m = 0; m < 4; ++m)
            a[m] = *reinterpret_cast<const short8v*>(As + (wr * 64 + m * 16 + lr) * 136 + koff);
#pragma unroll
        for (int n = 0; n < 4; ++n)
            b[n] = *reinterpret_cast<const short8v*>(Bs + (wc * 64 + n * 16 + lr) * 136 + koff);
#pragma unroll
        for (int m = 0; m < 4; ++m)
#pragma unroll
            for (int n = 0; n < 4; ++n)
                acc[m][n] = __builtin_amdgcn_mfma_f32_16x16x32_bf16(a[m], b[n], acc[m][n], 0, 0, 0);
    }

    // ---- epilogue ----
    if constexpr (PHASE == 0) {
        // rowsums of exp(2*dot), diagonal excluded
        float esum[4][4];
#pragma unroll
        for (int m = 0; m < 4; ++m)
#pragma unroll
            for (int r = 0; r < 4; ++r) esum[m][r] = 0.f;
#pragma unroll
        for (int m = 0; m < 4; ++m) {
#pragma unroll
            for (int n = 0; n < 4; ++n) {
#pragma unroll
                for (int r = 0; r < 4; ++r) {
                    int row_l = wr * 64 + m * 16 + lg * 4 + r;
                    int col_l = wc * 64 + n * 16 + lr;
                    float e = __expf(2.f * acc[m][n][r]);
                    if (!(bi == bj && row_l == col_l)) esum[m][r] += e;
                }
            }
        }
#pragma unroll
        for (int m = 0; m < 4; ++m)
#pragma unroll
            for (int r = 0; r < 4; ++r) {
                float v = esum[m][r];
                v += __shfl_xor(v, 1); v += __shfl_xor(v, 2);
                v += __shfl_xor(v, 4); v += __shfl_xor(v, 8);
                if (lr == 0)
                    Sp[(size_t)(bj * 2 + wc) * B + i0 + wr * 64 + m * 16 + lg * 4 + r] = v;
            }
    } else {
        float wloss = 0.f;
#pragma unroll
        for (int m = 0; m < 4; ++m) {
#pragma unroll
            for (int r = 0; r < 4; ++r) {
                int row_l = wr * 64 + m * 16 + lg * 4 + r;
                float Srow = Sv_s[row_l];
                unsigned mw0 = mask_s[row_l * 4 + wc * 2];
                unsigned mw1 = mask_s[row_l * 4 + wc * 2 + 1];
#pragma unroll
                for (int n = 0; n < 4; ++n) {
                    unsigned w = (n < 2) ? mw0 : mw1;
                    int bit = (n & 1) * 16 + lr;
                    if ((w >> bit) & 1u) {
                        float s = 2.f * acc[m][n][r];
                        wloss += log1pf(Srow * __expf(-s));
                    }
                }
            }
        }
        // block reduction of (wloss, pabr, pcnt)
#pragma unroll
        for (int m = 1; m < 64; m <<= 1) {
            wloss += __shfl_xor(wloss, m);
            pabr += __shfl_xor(pabr, m);
            pcnt += __shfl_xor(pcnt, m);
        }
        if (l == 0) { red_l[wave] = wloss; red_a[wave] = pabr; red_c[wave] = pcnt; }
        __syncthreads();
        if (tid == 0) {
            int bid = blockIdx.y * gridDim.x + blockIdx.x;
            bloss[bid] = red_l[0] + red_l[1] + red_l[2] + red_l[3];
            babr[bid] = red_a[0] + red_a[1] + red_a[2] + red_a[3];
            bcnt[bid] = red_c[0] + red_c[1] + red_c[2] + red_c[3];
        }
    }
}

// ---------------- reduce Sp slabs -> S ----------------
__global__ __launch_bounds__(256) void k_reduceS(const float* __restrict__ Sp,
                                                 float* __restrict__ S, int B) {
    int i = blockIdx.x * 256 + threadIdx.x;
    if (i >= B) return;
    float s = 0.f;
    for (int k = 0; k < 128; ++k) s += Sp[(size_t)k * B + i];
    S[i] = s;
}

// ---------------- final reduce over block partials ----------------
__global__ __launch_bounds__(256) void k_final(const unsigned int* __restrict__ bcnt,
                                               const float* __restrict__ babr,
                                               const float* __restrict__ bloss,
                                               float* __restrict__ out, int nblocks,
                                               float npairs) {
    __shared__ unsigned int sc[4];
    __shared__ float sab[4], slo[4];
    int tid = threadIdx.x;
    unsigned int c = 0;
    float ab = 0.f, lo = 0.f;
    for (int e = tid; e < nblocks; e += 256) {
        c += bcnt[e];
        ab += babr[e];
        lo += bloss[e];
    }
#pragma unroll
    for (int m = 1; m < 64; m <<= 1) {
        c += __shfl_xor(c, m);
        ab += __shfl_xor(ab, m);
        lo += __shfl_xor(lo, m);
    }
    int wave = tid >> 6, lane = tid & 63;
    if (lane == 0) { sc[wave] = c; sab[wave] = ab; slo[wave] = lo; }
    __syncthreads();
    if (tid == 0) {
        unsigned ctot = sc[0] + sc[1] + sc[2] + sc[3];
        float abt = sab[0] + sab[1] + sab[2] + sab[3];
        float lot = slo[0] + slo[1] + slo[2] + slo[3];
        float fn = (float)ctot;
        out[0] = ctot ? lot / fn : 0.f;
        out[1] = ctot ? abt / fn : 0.f;
        out[2] = fn;
        out[3] = fn / npairs;
    }
}

extern "C" void kernel_launch(void* const* d_in, const int* in_sizes, int n_in,
                              void* d_out, int out_size, void* d_ws, size_t ws_size,
                              hipStream_t stream) {
    const float* lat = (const float*)d_in[0];
    const float* abr = (const float*)d_in[1];
    float* out = (float*)d_out;
    int B = in_sizes[1] / ABR_D;  // 8192

    char* ws = (char*)d_ws;
    size_t off = 0;
    __hip_bfloat16* lnbf = (__hip_bfloat16*)(ws + off); off += (size_t)B * LAT_D * 2;  // 2 MB
    float* abrn = (float*)(ws + off);  off += (size_t)B * 8 * 4;                        // 256 KB
    float* Sp = (float*)(ws + off);    off += (size_t)128 * B * 4;                      // 4 MB
    float* Sg = (float*)(ws + off);    off += (size_t)B * 4;                            // 32 KB
    int nb = B / 128;                  // 64
    int nblocks = nb * nb;             // 4096
    unsigned* bcnt = (unsigned*)(ws + off); off += (size_t)nblocks * 4;
    float* babr = (float*)(ws + off);  off += (size_t)nblocks * 4;
    float* bloss = (float*)(ws + off); off += (size_t)nblocks * 4;

    k_norm_lat<<<B / 4, 256, 0, stream>>>(lat, lnbf, B);
    k_norm_abr<<<(B + 255) / 256, 256, 0, stream>>>(abr, abrn, B);

    dim3 g(nb, nb);
    k_gemm<0><<<g, 256, 69632, stream>>>(lnbf, nullptr, nullptr, Sp, nullptr, nullptr, nullptr, B);
    k_reduceS<<<B / 256, 256, 0, stream>>>(Sp, Sg, B);
    k_gemm<1><<<g, 256, 77824, stream>>>(lnbf, abrn, Sg, nullptr, bloss, babr, bcnt, B);
    k_final<<<1, 256, 0, stream>>>(bcnt, babr, bloss, out, nblocks, (float)B * (float)(B - 1));
}

// Round 3
// 235.984 us; speedup vs baseline: 2.2852x; 1.1490x over previous
//
#include <hip/hip_runtime.h>
#include <hip/hip_bf16.h>
#include <math.h>

#define LAT_D 128
#define SIM_THR 0.8f

typedef __attribute__((ext_vector_type(8))) short short8v;  // 8 bf16 = 4 VGPR
typedef __attribute__((ext_vector_type(4))) float f32x4;

__device__ __forceinline__ void glds16(const void* g, void* l) {
    __builtin_amdgcn_global_load_lds(
        (const __attribute__((address_space(1))) void*)g,
        (__attribute__((address_space(3))) void*)l, 16, 0, 0);
}

// ---------------- kernel 1: L2-normalize latent rows -> bf16 ----------------
__global__ __launch_bounds__(256) void k_norm_lat(const float* __restrict__ in,
                                                  __hip_bfloat16* __restrict__ out, int B) {
    int row = blockIdx.x * 4 + (threadIdx.x >> 6);
    int lane = threadIdx.x & 63;
    if (row >= B) return;
    float2 v = reinterpret_cast<const float2*>(in + (size_t)row * LAT_D)[lane];
    float ss = v.x * v.x + v.y * v.y;
#pragma unroll
    for (int m = 1; m < 64; m <<= 1) ss += __shfl_xor(ss, m);
    float sc = 1.0f / fmaxf(sqrtf(ss), 1e-12f);
    __hip_bfloat162 o;
    o.x = __float2bfloat16(v.x * sc);
    o.y = __float2bfloat16(v.y * sc);
    reinterpret_cast<__hip_bfloat162*>(out + (size_t)row * LAT_D)[lane] = o;
}

// ---------------- kernel 2: L2-normalize abr rows (6 dims) -> stride 8 ----------------
__global__ __launch_bounds__(256) void k_norm_abr(const float* __restrict__ in,
                                                  float* __restrict__ out, int B) {
    int row = blockIdx.x * 256 + threadIdx.x;
    if (row >= B) return;
    float v[6];
    float ss = 0.f;
#pragma unroll
    for (int d = 0; d < 6; ++d) { v[d] = in[(size_t)row * 6 + d]; ss += v[d] * v[d]; }
    float sc = 1.0f / fmaxf(sqrtf(ss), 1e-12f);
#pragma unroll
    for (int d = 0; d < 6; ++d) out[(size_t)row * 8 + d] = v[d] * sc;
    out[(size_t)row * 8 + 6] = 0.f;
    out[(size_t)row * 8 + 7] = 0.f;
}

// ---------------- single fused triangular GEMM pass ----------------
// Upper-triangle 128x128 tiles (bi <= bj). Per global row i accumulates:
//   accS[i]  += sum_j exp(2*dot_ij)   (diag excluded)
//   accC[i]  += #positives anchored at i
//   accSS[i] += sum over positives of s_ij = 2*dot_ij
//   accSM[i] += sum over positives of abr_sim_ij
// Off-diagonal tiles mirror contributions to columns (ordered pair (j,i)).
__global__ __launch_bounds__(256, 2) void k_gemm_tri(
    const __hip_bfloat16* __restrict__ lnbf,
    const float* __restrict__ abrn,
    float* __restrict__ accS, float* __restrict__ accSS,
    float* __restrict__ accC, float* __restrict__ accSM, int B)
{
    int bi = blockIdx.y, bj = blockIdx.x;
    if (bj < bi) return;
    bool diag = (bi == bj);

    extern __shared__ __hip_bfloat16 lds[];
    __hip_bfloat16* As = lds;                 // [128][128] linear (gload_lds dest)
    __hip_bfloat16* Bs = lds + 128 * LAT_D;
    __shared__ unsigned mask_s[512];          // [128 rows][4 words]

    int tid = threadIdx.x;
    int wave = tid >> 6, l = tid & 63;
    int i0 = bi * 128, j0 = bj * 128;

    // ---- abr j-rows into registers first (VMEM retires before gloads) ----
    int ti = tid >> 4, tj = tid & 15;
    float rj[8][6];
#pragma unroll
    for (int b2 = 0; b2 < 8; ++b2) {
        const float* p = abrn + (size_t)(j0 + tj * 8 + b2) * 8;
        float4 u0 = *reinterpret_cast<const float4*>(p);
        float2 u1 = *reinterpret_cast<const float2*>(p + 4);
        rj[b2][0] = u0.x; rj[b2][1] = u0.y; rj[b2][2] = u0.z;
        rj[b2][3] = u0.w; rj[b2][4] = u1.x; rj[b2][5] = u1.y;
    }

    // ---- stage A/B via global_load_lds, global source pre-swizzled ----
    // LDS chunk c of row r holds global chunk c ^ (r&7)  (16B chunks, involution)
    {
        int lrow = l >> 4, lch = l & 15;
        const __hip_bfloat16* Ag = lnbf + (size_t)i0 * LAT_D;
        const __hip_bfloat16* Bg = lnbf + (size_t)j0 * LAT_D;
#pragma unroll
        for (int c = 0; c < 8; ++c) {
            int rbase = wave * 32 + c * 4;      // wave-uniform LDS base row
            int row = rbase + lrow;
            int sch = lch ^ (row & 7);
            glds16(Ag + (size_t)row * LAT_D + sch * 8, As + rbase * LAT_D);
            glds16(Bg + (size_t)row * LAT_D + sch * 8, Bs + rbase * LAT_D);
        }
    }

    // ---- positive mask from fp32 abr sims (overlaps gload flight) ----
    unsigned colc[8]; float colsm[8];
#pragma unroll
    for (int b2 = 0; b2 < 8; ++b2) { colc[b2] = 0u; colsm[b2] = 0.f; }
#pragma unroll
    for (int a2 = 0; a2 < 8; ++a2) {
        int il = ti * 8 + a2, gi = i0 + il;
        const float* p = abrn + (size_t)gi * 8;
        float4 v0 = *reinterpret_cast<const float4*>(p);
        float2 v1 = *reinterpret_cast<const float2*>(p + 4);
        unsigned byte = 0, rc = 0; float rs = 0.f;
#pragma unroll
        for (int b2 = 0; b2 < 8; ++b2) {
            int gj = j0 + tj * 8 + b2;
            float sim = v0.x * rj[b2][0] + v0.y * rj[b2][1] + v0.z * rj[b2][2] +
                        v0.w * rj[b2][3] + v1.x * rj[b2][4] + v1.y * rj[b2][5];
            if (sim > SIM_THR && gi != gj) {
                byte |= 1u << b2; rc++; rs += sim;
                colc[b2]++; colsm[b2] += sim;
            }
        }
        unsigned wv = byte << ((tj & 3) * 8);
        wv |= __shfl_xor(wv, 1);
        wv |= __shfl_xor(wv, 2);
        if ((tj & 3) == 0) mask_s[il * 4 + (tj >> 2)] = wv;
        rc += __shfl_xor(rc, 1); rc += __shfl_xor(rc, 2);
        rc += __shfl_xor(rc, 4); rc += __shfl_xor(rc, 8);
        rs += __shfl_xor(rs, 1); rs += __shfl_xor(rs, 2);
        rs += __shfl_xor(rs, 4); rs += __shfl_xor(rs, 8);
        if (tj == 0 && rc) {
            atomicAdd(accC + gi, (float)rc);
            atomicAdd(accSM + gi, rs);
        }
    }
    if (!diag) {
        // mirrored ordered pairs (j, i): reduce over ti within wave, 4 waves add
#pragma unroll
        for (int b2 = 0; b2 < 8; ++b2) {
            unsigned cc = colc[b2]; float cs = colsm[b2];
            cc += __shfl_xor(cc, 16); cc += __shfl_xor(cc, 32);
            cs += __shfl_xor(cs, 16); cs += __shfl_xor(cs, 32);
            if (l < 16 && cc) {
                atomicAdd(accC + j0 + l * 8 + b2, (float)cc);
                atomicAdd(accSM + j0 + l * 8 + b2, cs);
            }
        }
    }
    __syncthreads();   // drains gloads; mask_s stable

    // ---- MFMA: each wave one 64x64 quadrant ----
    int wr = wave >> 1, wc = wave & 1;
    int lr = l & 15, lg = l >> 4;

    f32x4 acc[4][4];
#pragma unroll
    for (int m = 0; m < 4; ++m)
#pragma unroll
        for (int n = 0; n < 4; ++n) acc[m][n] = (f32x4){0.f, 0.f, 0.f, 0.f};

#pragma unroll
    for (int kk = 0; kk < 4; ++kk) {
        int ch = (kk * 4 + lg) ^ (lr & 7);     // swizzled 16B-chunk index
        short8v a[4], b[4];
#pragma unroll
        for (int m = 0; m < 4; ++m)
            a[m] = *reinterpret_cast<const short8v*>(As + (wr * 64 + m * 16 + lr) * LAT_D + ch * 8);
#pragma unroll
        for (int n = 0; n < 4; ++n)
            b[n] = *reinterpret_cast<const short8v*>(Bs + (wc * 64 + n * 16 + lr) * LAT_D + ch * 8);
#pragma unroll
        for (int m = 0; m < 4; ++m)
#pragma unroll
            for (int n = 0; n < 4; ++n)
                acc[m][n] = __builtin_amdgcn_mfma_f32_16x16x32_bf16(a[m], b[n], acc[m][n], 0, 0, 0);
    }

    // ---- epilogue: row partials (always) + col partials (off-diag mirror) ----
    float cse[4], css[4];
#pragma unroll
    for (int n = 0; n < 4; ++n) { cse[n] = 0.f; css[n] = 0.f; }
#pragma unroll
    for (int m = 0; m < 4; ++m) {
#pragma unroll
        for (int r = 0; r < 4; ++r) {
            int row_l = wr * 64 + m * 16 + lg * 4 + r;
            unsigned mw0 = mask_s[row_l * 4 + wc * 2];
            unsigned mw1 = mask_s[row_l * 4 + wc * 2 + 1];
            float esum = 0.f, sssum = 0.f;
#pragma unroll
            for (int n = 0; n < 4; ++n) {
                int col_l = wc * 64 + n * 16 + lr;
                float s2 = 2.f * acc[m][n][r];
                float e = __expf(s2);
                bool dg = diag && (row_l == col_l);
                if (!dg) { esum += e; cse[n] += e; }
                unsigned w = (n & 2) ? mw1 : mw0;
                if ((w >> ((n & 1) * 16 + lr)) & 1u) { sssum += s2; css[n] += s2; }
            }
            esum += __shfl_xor(esum, 1); esum += __shfl_xor(esum, 2);
            esum += __shfl_xor(esum, 4); esum += __shfl_xor(esum, 8);
            sssum += __shfl_xor(sssum, 1); sssum += __shfl_xor(sssum, 2);
            sssum += __shfl_xor(sssum, 4); sssum += __shfl_xor(sssum, 8);
            if (lr == 0) {
                atomicAdd(accS + i0 + row_l, esum);
                if (sssum != 0.f) atomicAdd(accSS + i0 + row_l, sssum);
            }
        }
    }
    if (!diag) {
#pragma unroll
        for (int n = 0; n < 4; ++n) {
            float e = cse[n], s = css[n];
            e += __shfl_xor(e, 16); e += __shfl_xor(e, 32);
            s += __shfl_xor(s, 16); s += __shfl_xor(s, 32);
            if (lg == 0) {
                atomicAdd(accS + j0 + wc * 64 + n * 16 + lr, e);
                if (s != 0.f) atomicAdd(accSS + j0 + wc * 64 + n * 16 + lr, s);
            }
        }
    }
}

// ---------------- per-row finalize + block partials ----------------
__global__ __launch_bounds__(256) void k_rows(const float* __restrict__ accS,
                                              const float* __restrict__ accSS,
                                              const float* __restrict__ accC,
                                              const float* __restrict__ accSM,
                                              float* __restrict__ pC, float* __restrict__ pSM,
                                              float* __restrict__ pLN, int B) {
    __shared__ float sc[4], sm[4], sl[4];
    int tid = threadIdx.x;
    int i = blockIdx.x * 256 + tid;
    float c = 0.f, m = 0.f, ln = 0.f;
    if (i < B) {
        c = accC[i]; m = accSM[i];
        ln = (c > 0.f) ? c * logf(accS[i]) - accSS[i] : 0.f;
    }
#pragma unroll
    for (int d = 1; d < 64; d <<= 1) {
        c += __shfl_xor(c, d); m += __shfl_xor(m, d); ln += __shfl_xor(ln, d);
    }
    int wave = tid >> 6, lane = tid & 63;
    if (lane == 0) { sc[wave] = c; sm[wave] = m; sl[wave] = ln; }
    __syncthreads();
    if (tid == 0) {
        pC[blockIdx.x] = sc[0] + sc[1] + sc[2] + sc[3];
        pSM[blockIdx.x] = sm[0] + sm[1] + sm[2] + sm[3];
        pLN[blockIdx.x] = sl[0] + sl[1] + sl[2] + sl[3];
    }
}

// ---------------- final ----------------
__global__ __launch_bounds__(64) void k_final(const float* __restrict__ pC,
                                              const float* __restrict__ pSM,
                                              const float* __restrict__ pLN,
                                              float* __restrict__ out, int nb, float npairs) {
    int tid = threadIdx.x;
    float c = 0.f, m = 0.f, ln = 0.f;
    if (tid < nb) { c = pC[tid]; m = pSM[tid]; ln = pLN[tid]; }
#pragma unroll
    for (int d = 1; d < 64; d <<= 1) {
        c += __shfl_xor(c, d); m += __shfl_xor(m, d); ln += __shfl_xor(ln, d);
    }
    if (tid == 0) {
        out[0] = (c > 0.f) ? ln / c : 0.f;
        out[1] = (c > 0.f) ? m / c : 0.f;
        out[2] = c;
        out[3] = c / npairs;
    }
}

extern "C" void kernel_launch(void* const* d_in, const int* in_sizes, int n_in,
                              void* d_out, int out_size, void* d_ws, size_t ws_size,
                              hipStream_t stream) {
    const float* lat = (const float*)d_in[0];
    const float* abr = (const float*)d_in[1];
    float* out = (float*)d_out;
    int B = in_sizes[1] / 6;  // 8192

    char* ws = (char*)d_ws;
    size_t off = 0;
    __hip_bfloat16* lnbf = (__hip_bfloat16*)(ws + off); off += (size_t)B * LAT_D * 2;  // 2 MB
    float* abrn = (float*)(ws + off); off += (size_t)B * 8 * 4;                         // 256 KB
    float* accS = (float*)(ws + off); off += (size_t)B * 4;
    float* accSS = (float*)(ws + off); off += (size_t)B * 4;
    float* accC = (float*)(ws + off); off += (size_t)B * 4;
    float* accSM = (float*)(ws + off); off += (size_t)B * 4;
    int nrb = B / 256;  // 32
    float* pC = (float*)(ws + off); off += (size_t)nrb * 4;
    float* pSM = (float*)(ws + off); off += (size_t)nrb * 4;
    float* pLN = (float*)(ws + off); off += (size_t)nrb * 4;

    hipMemsetAsync(accS, 0, (size_t)4 * B * 4, stream);  // zeros accS/accSS/accC/accSM

    k_norm_lat<<<B / 4, 256, 0, stream>>>(lat, lnbf, B);
    k_norm_abr<<<(B + 255) / 256, 256, 0, stream>>>(abr, abrn, B);

    int nb = B / 128;  // 64
    k_gemm_tri<<<dim3(nb, nb), 256, 65536, stream>>>(lnbf, abrn, accS, accSS, accC, accSM, B);
    k_rows<<<nrb, 256, 0, stream>>>(accS, accSS, accC, accSM, pC, pSM, pLN, B);
    k_final<<<1, 64, 0, stream>>>(pC, pSM, pLN, out, nrb, (float)B * (float)(B - 1));
}

// Round 4
// 80.676 us; speedup vs baseline: 6.6843x; 2.9251x over previous
//
#include <hip/hip_runtime.h>
#include <hip/hip_bf16.h>
#include <math.h>

#define SIM_THR 0.8f

typedef __attribute__((ext_vector_type(8))) short short8v;   // 8 bf16
typedef __attribute__((ext_vector_type(4))) float f32x4;
typedef __attribute__((ext_vector_type(4))) _Float16 half4v; // 4 f16

__device__ __forceinline__ void glds16(const void* g, void* l) {
    __builtin_amdgcn_global_load_lds(
        (const __attribute__((address_space(1))) void*)g,
        (__attribute__((address_space(3))) void*)l, 16, 0, 0);
}

// ---------------- kernel 1: L2-normalize latent rows -> bf16 ----------------
__global__ __launch_bounds__(256) void k_norm_lat(const float* __restrict__ in,
                                                  __hip_bfloat16* __restrict__ out, int B) {
    int row = blockIdx.x * 4 + (threadIdx.x >> 6);
    int lane = threadIdx.x & 63;
    if (row >= B) return;
    float2 v = reinterpret_cast<const float2*>(in + (size_t)row * 128)[lane];
    float ss = v.x * v.x + v.y * v.y;
#pragma unroll
    for (int m = 1; m < 64; m <<= 1) ss += __shfl_xor(ss, m);
    float sc = 1.0f / fmaxf(sqrtf(ss), 1e-12f);
    __hip_bfloat162 o;
    o.x = __float2bfloat16(v.x * sc);
    o.y = __float2bfloat16(v.y * sc);
    reinterpret_cast<__hip_bfloat162*>(out + (size_t)row * 128)[lane] = o;
}

// ---------------- kernel 2: L2-normalize abr rows -> f16, K padded to 16 ----------------
__global__ __launch_bounds__(256) void k_norm_abr(const float* __restrict__ in,
                                                  _Float16* __restrict__ out, int B) {
    int row = blockIdx.x * 256 + threadIdx.x;
    if (row >= B) return;
    float v[6];
    float ss = 0.f;
#pragma unroll
    for (int d = 0; d < 6; ++d) { v[d] = in[(size_t)row * 6 + d]; ss += v[d] * v[d]; }
    float sc = 1.0f / fmaxf(sqrtf(ss), 1e-12f);
#pragma unroll
    for (int d = 0; d < 6; ++d) out[(size_t)row * 16 + d] = (_Float16)(v[d] * sc);
#pragma unroll
    for (int d = 6; d < 16; ++d) out[(size_t)row * 16 + d] = (_Float16)0.f;
}

// ---------------- fused sweep: block (jc, bi) owns rows [bi*128, +128), sweeps 8 j-tiles ----
// Per row accumulates: esum (=S_i partial, diag excl), sum_d over positives, cnt, sum_sim.
// Writes ONE float4 per (row, wc-half) to slab[(jc*2+wc)*B + row]. No atomics anywhere.
__global__ __launch_bounds__(256, 2) void k_sweep(
    const __hip_bfloat16* __restrict__ lnbf,
    const _Float16* __restrict__ abrf,
    float4* __restrict__ slab, int B)
{
    extern __shared__ char lds[];
    __hip_bfloat16* Alat = (__hip_bfloat16*)lds;            // 32768 B
    __hip_bfloat16* Blat = (__hip_bfloat16*)(lds + 32768);  // 32768 B
    _Float16* Aabr = (_Float16*)(lds + 65536);              // 4096 B
    _Float16* Babr = (_Float16*)(lds + 69632);              // 4096 B

    int jc = blockIdx.x, bi = blockIdx.y;
    int i0 = bi * 128;
    int tid = threadIdx.x;
    int w = tid >> 6, l = tid & 63;
    int lr = l & 15, lg = l >> 4;
    int wr = w >> 1, wc = w & 1;
    int lrow = l >> 4, lch = l & 15;

    // ---- prologue: stage A panels (once) + B panels for tile 0 ----
    {
        int j0 = jc * 8 * 128;
#pragma unroll
        for (int c = 0; c < 8; ++c) {
            int rbase = w * 32 + c * 4;
            int row = rbase + lrow;
            int sch = lch ^ (row & 7);
            glds16(lnbf + (size_t)(i0 + row) * 128 + sch * 8, Alat + rbase * 128);
            glds16(lnbf + (size_t)(j0 + row) * 128 + sch * 8, Blat + rbase * 128);
        }
        glds16(abrf + (size_t)(i0 + w * 32 + (l >> 1)) * 16 + (l & 1) * 8, Aabr + w * 512);
        glds16(abrf + (size_t)(j0 + w * 32 + (l >> 1)) * 16 + (l & 1) * 8, Babr + w * 512);
    }
    __syncthreads();

    float esum_r[4][4] = {{0.f}}, sumd_r[4][4] = {{0.f}};
    float cnt_r[4][4] = {{0.f}}, sumsim_r[4][4] = {{0.f}};

    // A abr frags are loop-invariant
    half4v aa[4];
#pragma unroll
    for (int m = 0; m < 4; ++m)
        aa[m] = *reinterpret_cast<const half4v*>(Aabr + (wr * 64 + m * 16 + lr) * 16 + lg * 4);

#pragma unroll 1
    for (int t = 0; t < 8; ++t) {
        bool dtile = (jc * 8 + t) == bi;

        // ---- [1] abr MFMA + positive-predicate epilogue ----
        unsigned pm0 = 0, pm1 = 0;
        {
            half4v bb[4];
#pragma unroll
            for (int n = 0; n < 4; ++n)
                bb[n] = *reinterpret_cast<const half4v*>(Babr + (wc * 64 + n * 16 + lr) * 16 + lg * 4);
#pragma unroll
            for (int m = 0; m < 4; ++m) {
#pragma unroll
                for (int n = 0; n < 4; ++n) {
#if __has_builtin(__builtin_amdgcn_mfma_f32_16x16x16f16)
                    f32x4 aacc = __builtin_amdgcn_mfma_f32_16x16x16f16(
                        aa[m], bb[n], (f32x4){0.f, 0.f, 0.f, 0.f}, 0, 0, 0);
#else
                    f32x4 aacc;
#pragma unroll
                    for (int r = 0; r < 4; ++r) {
                        int row_l = wr * 64 + m * 16 + lg * 4 + r;
                        int col_l = wc * 64 + n * 16 + lr;
                        float s = 0.f;
#pragma unroll
                        for (int k = 0; k < 6; ++k)
                            s += (float)Aabr[row_l * 16 + k] * (float)Babr[col_l * 16 + k];
                        aacc[r] = s;
                    }
#endif
#pragma unroll
                    for (int r = 0; r < 4; ++r) {
                        float sim = aacc[r];
                        int row_l = wr * 64 + m * 16 + lg * 4 + r;
                        int col_l = wc * 64 + n * 16 + lr;
                        bool pred = (sim > SIM_THR) && !(dtile && row_l == col_l);
                        if (pred) { cnt_r[m][r] += 1.f; sumsim_r[m][r] += sim; }
                        unsigned bit = pred ? 1u : 0u;
                        int e = (m & 1) * 16 + n * 4 + r;
                        if (m < 2) pm0 |= bit << e; else pm1 |= bit << e;
                    }
                }
            }
        }

        // ---- [2] latent MFMA ----
        f32x4 acc[4][4];
#pragma unroll
        for (int m = 0; m < 4; ++m)
#pragma unroll
            for (int n = 0; n < 4; ++n) acc[m][n] = (f32x4){0.f, 0.f, 0.f, 0.f};
#pragma unroll
        for (int kk = 0; kk < 4; ++kk) {
            int ch = (kk * 4 + lg) ^ (lr & 7);
            short8v a[4], b[4];
#pragma unroll
            for (int m = 0; m < 4; ++m)
                a[m] = *reinterpret_cast<const short8v*>(Alat + (wr * 64 + m * 16 + lr) * 128 + ch * 8);
#pragma unroll
            for (int n = 0; n < 4; ++n)
                b[n] = *reinterpret_cast<const short8v*>(Blat + (wc * 64 + n * 16 + lr) * 128 + ch * 8);
#pragma unroll
            for (int m = 0; m < 4; ++m)
#pragma unroll
                for (int n = 0; n < 4; ++n)
                    acc[m][n] = __builtin_amdgcn_mfma_f32_16x16x32_bf16(a[m], b[n], acc[m][n], 0, 0, 0);
        }
        __syncthreads();   // [3] all frag reads done -> B LDS reusable

        // ---- [4] issue next tile's staging (flight hidden under epilogue) ----
        if (t < 7) {
            int j0n = (jc * 8 + t + 1) * 128;
#pragma unroll
            for (int c = 0; c < 8; ++c) {
                int rbase = w * 32 + c * 4;
                int row = rbase + lrow;
                int sch = lch ^ (row & 7);
                glds16(lnbf + (size_t)(j0n + row) * 128 + sch * 8, Blat + rbase * 128);
            }
            glds16(abrf + (size_t)(j0n + w * 32 + (l >> 1)) * 16 + (l & 1) * 8, Babr + w * 512);
        }

        // ---- [5] main epilogue (registers only) ----
#pragma unroll
        for (int m = 0; m < 4; ++m) {
            unsigned pmw = (m < 2) ? pm0 : pm1;
#pragma unroll
            for (int n = 0; n < 4; ++n) {
#pragma unroll
                for (int r = 0; r < 4; ++r) {
                    float d = acc[m][n][r];
                    int row_l = wr * 64 + m * 16 + lg * 4 + r;
                    int col_l = wc * 64 + n * 16 + lr;
                    float e2 = __expf(2.f * d);
                    if (dtile && row_l == col_l) e2 = 0.f;
                    esum_r[m][r] += e2;
                    if ((pmw >> ((m & 1) * 16 + n * 4 + r)) & 1u) sumd_r[m][r] += d;
                }
            }
        }
        if (t < 7) __syncthreads();   // [6] next B ready (compiler drains vmcnt)
    }

    // ---- final: reduce over lr (16 lanes share a row-group's columns) and store once ----
#pragma unroll
    for (int m = 0; m < 4; ++m)
#pragma unroll
        for (int r = 0; r < 4; ++r) {
            float a0 = esum_r[m][r], a1 = sumd_r[m][r], a2 = cnt_r[m][r], a3 = sumsim_r[m][r];
#pragma unroll
            for (int d2 = 1; d2 < 16; d2 <<= 1) {
                a0 += __shfl_xor(a0, d2);
                a1 += __shfl_xor(a1, d2);
                a2 += __shfl_xor(a2, d2);
                a3 += __shfl_xor(a3, d2);
            }
            if (lr == 0) {
                int row_g = i0 + wr * 64 + m * 16 + lg * 4 + r;
                slab[(size_t)(jc * 2 + wc) * B + row_g] = make_float4(a0, a1, a2, a3);
            }
        }
}

// ---------------- per-row finalize + block partials ----------------
__global__ __launch_bounds__(256) void k_rows(const float4* __restrict__ slab,
                                              float* __restrict__ pC, float* __restrict__ pSM,
                                              float* __restrict__ pLN, int B) {
    __shared__ float sc[4], sm[4], sl[4];
    int tid = threadIdx.x;
    int i = blockIdx.x * 256 + tid;
    float S = 0.f, sd = 0.f, c = 0.f, smm = 0.f;
#pragma unroll
    for (int k = 0; k < 16; ++k) {
        float4 v = slab[(size_t)k * B + i];
        S += v.x; sd += v.y; c += v.z; smm += v.w;
    }
    float ln = (c > 0.f) ? c * logf(S) - 2.f * sd : 0.f;
#pragma unroll
    for (int d = 1; d < 64; d <<= 1) {
        c += __shfl_xor(c, d); smm += __shfl_xor(smm, d); ln += __shfl_xor(ln, d);
    }
    int wave = tid >> 6, lane = tid & 63;
    if (lane == 0) { sc[wave] = c; sm[wave] = smm; sl[wave] = ln; }
    __syncthreads();
    if (tid == 0) {
        pC[blockIdx.x] = sc[0] + sc[1] + sc[2] + sc[3];
        pSM[blockIdx.x] = sm[0] + sm[1] + sm[2] + sm[3];
        pLN[blockIdx.x] = sl[0] + sl[1] + sl[2] + sl[3];
    }
}

// ---------------- final ----------------
__global__ __launch_bounds__(64) void k_final(const float* __restrict__ pC,
                                              const float* __restrict__ pSM,
                                              const float* __restrict__ pLN,
                                              float* __restrict__ out, int nb, float npairs) {
    int tid = threadIdx.x;
    float c = 0.f, m = 0.f, ln = 0.f;
    if (tid < nb) { c = pC[tid]; m = pSM[tid]; ln = pLN[tid]; }
#pragma unroll
    for (int d = 1; d < 64; d <<= 1) {
        c += __shfl_xor(c, d); m += __shfl_xor(m, d); ln += __shfl_xor(ln, d);
    }
    if (tid == 0) {
        out[0] = (c > 0.f) ? ln / c : 0.f;
        out[1] = (c > 0.f) ? m / c : 0.f;
        out[2] = c;
        out[3] = c / npairs;
    }
}

extern "C" void kernel_launch(void* const* d_in, const int* in_sizes, int n_in,
                              void* d_out, int out_size, void* d_ws, size_t ws_size,
                              hipStream_t stream) {
    const float* lat = (const float*)d_in[0];
    const float* abr = (const float*)d_in[1];
    float* out = (float*)d_out;
    int B = in_sizes[1] / 6;  // 8192

    char* ws = (char*)d_ws;
    size_t off = 0;
    __hip_bfloat16* lnbf = (__hip_bfloat16*)(ws + off); off += (size_t)B * 128 * 2;  // 2 MB
    _Float16* abrf = (_Float16*)(ws + off); off += (size_t)B * 16 * 2;               // 256 KB
    float4* slab = (float4*)(ws + off); off += (size_t)16 * B * 16;                  // 2 MB
    int nrb = B / 256;  // 32
    float* pC = (float*)(ws + off); off += (size_t)nrb * 4;
    float* pSM = (float*)(ws + off); off += (size_t)nrb * 4;
    float* pLN = (float*)(ws + off); off += (size_t)nrb * 4;

    k_norm_lat<<<B / 4, 256, 0, stream>>>(lat, lnbf, B);
    k_norm_abr<<<(B + 255) / 256, 256, 0, stream>>>(abr, abrf, B);
    k_sweep<<<dim3(8, B / 128), 256, 73728, stream>>>(lnbf, abrf, slab, B);
    k_rows<<<nrb, 256, 0, stream>>>(slab, pC, pSM, pLN, B);
    k_final<<<1, 64, 0, stream>>>(pC, pSM, pLN, out, nrb, (float)B * (float)(B - 1));
}